// Round 9
// baseline (4394.658 us; speedup 1.0000x reference)
//
#include <hip/hip_runtime.h>

#define SEQ 2048
#define D 128

// ---------------------------------------------------------------------------
// Kernel 1: per-step J-independent quantities (fully parallel), UNNORMALIZED:
//   alpha_i  = k_s . q_i      (i <= s)
//   kqq[s]   = sum alpha_i^2          = l * (k^T Sqq_l k)
//   sl[s]    = sum alpha_i (v_s.v_i)  = l * (k^T Sqv_l v)
//   vv[s]    = v_s . v_s
//   U[s][c]  = sum_i q_i[c] alpha_i   = l * (Sqq_l k)[c]
//   invl[s]  = 1.0 / l   (fp64, for cost rescale)
// Adjacency scalars (for the scan's lagged-matvec corrections):
//   kq_adj[s] = k_{s-1} . q_s ; vv_adj[s] = v_s . v_{s-1} ; kU_adj[s] = k_{s-1} . U_s
// ---------------------------------------------------------------------------
__global__ __launch_bounds__(256) void precompute_kernel(
    const float* __restrict__ q, const float* __restrict__ k, const float* __restrict__ v,
    float* __restrict__ U, float* __restrict__ sl, float* __restrict__ kqq,
    float* __restrict__ vv, float* __restrict__ kq_adj, float* __restrict__ vv_adj,
    float* __restrict__ kU_adj, double* __restrict__ invl)
{
    const int s = blockIdx.x;
    const int tid = threadIdx.x;

    __shared__ float ks[D];
    __shared__ float vs[D];
    __shared__ float alpha[SEQ];
    __shared__ float red[8];
    __shared__ float upart[256];

    if (tid < D) ks[tid] = k[s * D + tid];
    else if (tid < 2 * D) vs[tid - D] = v[s * D + (tid - D)];
    __syncthreads();

    float p_a2 = 0.f, p_ab = 0.f;
    for (int i = tid; i <= s; i += 256) {
        const float4* qr = (const float4*)(q + (size_t)i * D);
        const float4* vr = (const float4*)(v + (size_t)i * D);
        float a = 0.f, b = 0.f;
#pragma unroll
        for (int j = 0; j < D / 4; ++j) {
            float4 q4 = qr[j];
            float4 v4 = vr[j];
            a += q4.x * ks[4 * j + 0] + q4.y * ks[4 * j + 1] + q4.z * ks[4 * j + 2] + q4.w * ks[4 * j + 3];
            b += v4.x * vs[4 * j + 0] + v4.y * vs[4 * j + 1] + v4.z * vs[4 * j + 2] + v4.w * vs[4 * j + 3];
        }
        alpha[i] = a;
        p_a2 += a * a;
        p_ab += a * b;
        if (i == s) vv[s] = b;  // v_s . v_s
    }
#pragma unroll
    for (int off = 1; off < 64; off <<= 1) {
        p_a2 += __shfl_xor(p_a2, off);
        p_ab += __shfl_xor(p_ab, off);
    }
    const int wid = tid >> 6;
    if ((tid & 63) == 0) { red[wid] = p_a2; red[4 + wid] = p_ab; }
    __syncthreads();  // also makes alpha[] visible to everyone
    if (tid == 0) {
        kqq[s] = red[0] + red[1] + red[2] + red[3];
        sl[s]  = red[4] + red[5] + red[6] + red[7];
        invl[s] = 1.0 / (double)(s + 1);
    }

    // ---- adjacency dots: wave 0 -> kq_adj[s+1], wave 1 -> vv_adj[s] ----
    if (tid < 64) {
        if (s + 1 < SEQ) {
            float p2 = ks[tid] * q[(size_t)(s + 1) * D + tid]
                     + ks[tid + 64] * q[(size_t)(s + 1) * D + 64 + tid];
#pragma unroll
            for (int off = 1; off < 64; off <<= 1) p2 += __shfl_xor(p2, off);
            if (tid == 0) kq_adj[s + 1] = p2;
        }
        if (s == 0 && tid == 0) { kq_adj[0] = 0.f; kU_adj[0] = 0.f; vv_adj[0] = 0.f; }
    } else if (tid < 128 && s > 0) {
        const int t2 = tid - 64;
        float p2 = vs[t2] * v[(size_t)(s - 1) * D + t2]
                 + vs[t2 + 64] * v[(size_t)(s - 1) * D + 64 + t2];
#pragma unroll
        for (int off = 1; off < 64; off <<= 1) p2 += __shfl_xor(p2, off);
        if (t2 == 0) vv_adj[s] = p2;
    }

    // pass 2: U[s][c] = sum_i q[i][c] * alpha[i], i parity-split over h,
    // 4 independent accumulators to break the dependent fma chain
    const int c = tid & (D - 1);
    const int h = tid >> 7;  // 0 or 1
    float a0 = 0.f, a1 = 0.f, a2 = 0.f, a3 = 0.f;
    int i = h;
    for (; i + 6 <= s; i += 8) {
        a0 = fmaf(q[(size_t)(i    ) * D + c], alpha[i    ], a0);
        a1 = fmaf(q[(size_t)(i + 2) * D + c], alpha[i + 2], a1);
        a2 = fmaf(q[(size_t)(i + 4) * D + c], alpha[i + 4], a2);
        a3 = fmaf(q[(size_t)(i + 6) * D + c], alpha[i + 6], a3);
    }
    for (; i <= s; i += 2) a0 = fmaf(q[(size_t)i * D + c], alpha[i], a0);
    upart[tid] = (a0 + a1) + (a2 + a3);
    __syncthreads();

    // U store + kU_adj[s] = k_{s-1}.U_s
    float kup = 0.f;
    if (tid < D) {
        const float uv = upart[tid] + upart[tid + D];
        U[(size_t)s * D + tid] = uv;
        if (s > 0) kup = uv * k[(size_t)(s - 1) * D + tid];
    }
#pragma unroll
    for (int off = 1; off < 64; off <<= 1) kup += __shfl_xor(kup, off);
    if (tid == 0)  red[0] = kup;
    if (tid == 64) red[1] = kup;
    __syncthreads();
    if (s > 0 && tid == 0) kU_adj[s] = red[0] + red[1];
}

// ---------------------------------------------------------------------------
// Kernel 2: sequential scan, 1024 threads (16 waves, 4/SIMD).
// ROUND-9 = R8's lagged-matvec skeleton + two fixes:
//  (1) SWIZZLED ring: chunk cg at float offset cg*20 (row stride 160).
//      Per ds_read_b128, lanes' starting banks = {0,20,8,28,16,4,24,12} —
//      conflict-free (R8 had 770 conflict-cyc/step at c0=cg*16).
//  (2) ONE barrier/step: the fp64 chain runs REDUNDANTLY on all threads
//      (inputs are shared wred + uniform s_loads -> bit-identical), so dec
//      lands in registers everywhere; B2 + decLDS broadcast deleted.
// Hazards: ring write (phase i+2, pre-B(i)) vs read (iter i+2, post-B(i+1)):
// >=1 barrier apart; overwrite of phase (i+2)%3 vs its last read (iter i-1,
// pre-B(i-1)): barrier B(i-1) between. wred parity-double-buffered.
// ---------------------------------------------------------------------------
__global__ __launch_bounds__(1024, 4) void scan_kernel(
    const float* __restrict__ q, const float* __restrict__ k, const float* __restrict__ v,
    const float* __restrict__ U, const float* __restrict__ sl_arr,
    const float* __restrict__ kqq_arr, const float* __restrict__ vv_arr,
    const float* __restrict__ kq_adj, const float* __restrict__ vv_adj,
    const float* __restrict__ kU_adj, const double* __restrict__ invl_arr,
    float* __restrict__ out)  // [0,2048) costs | [2048,4096) updated | [4096,...) J
{
    const int tid  = threadIdx.x;
    const int lane = tid & 63;
    const int r    = tid >> 3;        // my row 0..127
    const int cg   = tid & 7;
    const int c0s  = cg * 20;         // swizzled LDS chunk offset (16 floats used)

    float4 jr0 = make_float4(0.f, 0.f, 0.f, 0.f);
    float4 jr1 = jr0, jr2 = jr0, jr3 = jr0;

    __shared__ float ring[3][3][160];        // [phase][q,u,k][swizzled 128]
    __shared__ __align__(16) float wred[2][16][4];

    const bool stager = tid < 384;
    const int  which  = tid >> 7;     // 0:q 1:u 2:k (for tid<384)
    const int  sidx   = tid & 127;
    const int  widx   = ((sidx >> 4) * 20) + (sidx & 15);  // swizzled write idx

    // ---- prologue: stage phases 0,1; gstage holds phase-2 data ----
    // invariant: phase j holds q_{j+1}, u_{j+1}, k_j
    float gstage = 0.f;
    if (stager) {
        if (which == 0) {
            ring[0][0][widx] = q[(size_t)1 * D + sidx];
            ring[1][0][widx] = q[(size_t)2 * D + sidx];
            gstage = q[(size_t)3 * D + sidx];
        } else if (which == 1) {
            ring[0][1][widx] = U[(size_t)1 * D + sidx];
            ring[1][1][widx] = U[(size_t)2 * D + sidx];
            gstage = U[(size_t)3 * D + sidx];
        } else {
            ring[0][2][widx] = k[sidx];
            ring[1][2][widx] = k[(size_t)1 * D + sidx];
            gstage = k[(size_t)2 * D + sidx];
        }
    }
    float vcur = v[r], vnext = v[(size_t)D + r], vn2 = v[(size_t)2 * D + r];

    // dec_0 is always mode 2 (first step: J_0 = v_0 k_0^T)
    float dwf = 0.f, dwi = 1.f;
    int dmode = 2;

    // step-0 scalar state, identical on ALL threads
    double SJ, AJJ, trSvv;
    {
        const double sl0 = (double)sl_arr[0];
        const double kq0 = (double)kqq_arr[0];
        const double vv0 = (double)vv_arr[0];
        trSvv = vv0;
        SJ  = sl0;
        AJJ = vv0 * kq0;
        if (tid == 0) {
            out[0] = (float)((0.5 * trSvv - SJ + 0.5 * AJJ) * invl_arr[0]);
            out[SEQ] = 1.f;
        }
    }
    __syncthreads();

    for (int i = 0; i < SEQ - 1; ++i) {
        const int p   = i % 3;
        const int pw  = (i + 2) % 3;
        const int par = i & 1;

        // ---- chain scalars: uniform -> s_loads, issued early ----
        const float  c_sl  = sl_arr[i + 1];
        const float  c_kq  = kqq_arr[i + 1];
        const float  c_vv  = vv_arr[i + 1];
        const float  c_kqa = kq_adj[i + 1];
        const float  c_vva = vv_adj[i + 1];
        const float  c_vvp = vv_arr[i];
        const float  c_kua = kU_adj[i + 1];
        const double c_inv = invl_arr[i + 1];

        // ---- dot: Y' = J_{i-1} q_{i+1}, W' = J_{i-1} u_{i+1} (swizzled ring)
        const float4* q4 = (const float4*)&ring[p][0][c0s];
        const float4* u4 = (const float4*)&ring[p][1][c0s];
        const float4 qa = q4[0], qb = q4[1], qc = q4[2], qd = q4[3];
        const float4 ua = u4[0], ub = u4[1], uc = u4[2], ud = u4[3];
        float pa = jr0.x * qa.x, pb = jr2.x * qc.x;
        pa = fmaf(jr0.y, qa.y, pa); pb = fmaf(jr2.y, qc.y, pb);
        pa = fmaf(jr0.z, qa.z, pa); pb = fmaf(jr2.z, qc.z, pb);
        pa = fmaf(jr0.w, qa.w, pa); pb = fmaf(jr2.w, qc.w, pb);
        pa = fmaf(jr1.x, qb.x, pa); pb = fmaf(jr3.x, qd.x, pb);
        pa = fmaf(jr1.y, qb.y, pa); pb = fmaf(jr3.y, qd.y, pb);
        pa = fmaf(jr1.z, qb.z, pa); pb = fmaf(jr3.z, qd.z, pb);
        pa = fmaf(jr1.w, qb.w, pa); pb = fmaf(jr3.w, qd.w, pb);
        const float pq = pa + pb;
        float va_ = jr0.x * ua.x, vb_ = jr2.x * uc.x;
        va_ = fmaf(jr0.y, ua.y, va_); vb_ = fmaf(jr2.y, uc.y, vb_);
        va_ = fmaf(jr0.z, ua.z, va_); vb_ = fmaf(jr2.z, uc.z, vb_);
        va_ = fmaf(jr0.w, ua.w, va_); vb_ = fmaf(jr2.w, uc.w, vb_);
        va_ = fmaf(jr1.x, ub.x, va_); vb_ = fmaf(jr3.x, ud.x, vb_);
        va_ = fmaf(jr1.y, ub.y, va_); vb_ = fmaf(jr3.y, ud.y, vb_);
        va_ = fmaf(jr1.z, ub.z, va_); vb_ = fmaf(jr3.z, ud.z, vb_);
        va_ = fmaf(jr1.w, ub.w, va_); vb_ = fmaf(jr3.w, ud.w, vb_);
        const float pu = va_ + vb_;

        // ---- combine over cg (bits 0..2): full row values on all 8 lanes --
        float Yq = pq;
        Yq += __shfl_xor(Yq, 1); Yq += __shfl_xor(Yq, 2); Yq += __shfl_xor(Yq, 4);
        float Yw = pu;
        Yw += __shfl_xor(Yw, 1); Yw += __shfl_xor(Yw, 2); Yw += __shfl_xor(Yw, 4);

        // ---- roles (one count per row), row-reduce (bits 3..5) ----
        float z = (cg == 0) ? vnext * Yq
                : (cg == 1) ? Yq * Yq
                : (cg == 2) ? vcur * Yq
                : (cg == 3) ? vnext * Yw : 0.f;
        z += __shfl_xor(z, 8); z += __shfl_xor(z, 16); z += __shfl_xor(z, 32);
        if (lane < 4) wred[par][tid >> 6][lane] = z;

        // ---- update J_{i-1} -> J_i with dec_i (k_i from ring, swizzled) ----
        const float4* k4 = (const float4*)&ring[p][2][c0s];
        const float4 kk0 = k4[0], kk1 = k4[1], kk2 = k4[2], kk3 = k4[3];
        if (dmode == 2) {
            jr0.x = vcur*kk0.x; jr0.y = vcur*kk0.y; jr0.z = vcur*kk0.z; jr0.w = vcur*kk0.w;
            jr1.x = vcur*kk1.x; jr1.y = vcur*kk1.y; jr1.z = vcur*kk1.z; jr1.w = vcur*kk1.w;
            jr2.x = vcur*kk2.x; jr2.y = vcur*kk2.y; jr2.z = vcur*kk2.z; jr2.w = vcur*kk2.w;
            jr3.x = vcur*kk3.x; jr3.y = vcur*kk3.y; jr3.z = vcur*kk3.z; jr3.w = vcur*kk3.w;
        } else if (dmode == 1) {
            const float wvr = dwi * vcur;
            jr0.x = fmaf(jr0.x, dwf, wvr*kk0.x); jr0.y = fmaf(jr0.y, dwf, wvr*kk0.y);
            jr0.z = fmaf(jr0.z, dwf, wvr*kk0.z); jr0.w = fmaf(jr0.w, dwf, wvr*kk0.w);
            jr1.x = fmaf(jr1.x, dwf, wvr*kk1.x); jr1.y = fmaf(jr1.y, dwf, wvr*kk1.y);
            jr1.z = fmaf(jr1.z, dwf, wvr*kk1.z); jr1.w = fmaf(jr1.w, dwf, wvr*kk1.w);
            jr2.x = fmaf(jr2.x, dwf, wvr*kk2.x); jr2.y = fmaf(jr2.y, dwf, wvr*kk2.y);
            jr2.z = fmaf(jr2.z, dwf, wvr*kk2.z); jr2.w = fmaf(jr2.w, dwf, wvr*kk2.w);
            jr3.x = fmaf(jr3.x, dwf, wvr*kk3.x); jr3.y = fmaf(jr3.y, dwf, wvr*kk3.y);
            jr3.z = fmaf(jr3.z, dwf, wvr*kk3.z); jr3.w = fmaf(jr3.w, dwf, wvr*kk3.w);
        }

        // ---- staging write (phase i+2) + next prefetches ----
        if (stager) {
            ring[pw][which][widx] = gstage;
            const int tq = (i + 4 < SEQ) ? i + 4 : SEQ - 1;
            const int tk = (i + 3 < SEQ) ? i + 3 : SEQ - 1;
            gstage = (which == 0) ? q[(size_t)tq * D + sidx]
                   : (which == 1) ? U[(size_t)tq * D + sidx]
                                  : k[(size_t)tk * D + sidx];
        }
        const int tv = (i + 3 < SEQ) ? i + 3 : SEQ - 1;
        const float vnew = v[(size_t)tv * D + r];

        __syncthreads();  // the ONE barrier

        // ---- cross-reduce (ALL waves): 1 float4 broadcast read + 4 levels --
        const int t = lane & 15;
        float4 ww = *(const float4*)&wred[par][t][0];
#pragma unroll
        for (int off = 1; off < 16; off <<= 1) {
            ww.x += __shfl_xor(ww.x, off);
            ww.y += __shfl_xor(ww.y, off);
            ww.z += __shfl_xor(ww.z, off);
            ww.w += __shfl_xor(ww.w, off);
        }

        // ---- corrections with dec_i (identical on all threads) ----
        double a, b;
        if (dmode == 2)      { a = 0.0; b = 1.0; }
        else if (dmode == 1) { a = (double)dwf; b = (double)dwi; }
        else                 { a = 1.0; b = 0.0; }
        const double kqa = (double)c_kqa, vva = (double)c_vva;
        const double vvp = (double)c_vvp, kua = (double)c_kua;
        const double r1 = (double)ww.x, r2 = (double)ww.y;
        const double r3 = (double)ww.z, r4 = (double)ww.w;
        const double Jqv  = a * r1 + b * (kqa * vva);
        const double Jq2  = a * a * r2 + 2.0 * a * b * kqa * r3 + b * b * kqa * kqa * vvp;
        const double AJl_ = a * r4 + b * kua * vva;

        // ---- fp64 decision chain (step i+1, never "first"; all threads) ----
        trSvv += (double)c_vv;
        SJ    += Jqv;
        AJJ   += Jq2;
        const double s_l  = (double)c_sl;
        const double A_ll = (double)c_vv * (double)c_kq;
        const double AJJ_s  = (AJJ == 0.0)  ? 1.0 : AJJ;
        const double A_ll_s = (A_ll == 0.0) ? 1.0 : A_ll;
        const double denom   = AJJ * A_ll - AJl_ * AJl_;
        const double denom_s = (denom == 0.0) ? 1.0 : denom;
        const double rden = 1.0 / denom_s;
        const double wf = (A_ll * SJ - AJl_ * s_l) * rden;
        const double wi = (AJJ * s_l - AJl_ * SJ) * rden;
        double wf_c, wi_c;
        if (wi <= 0.0)      { wf_c = SJ / AJJ_s;  wi_c = 0.0; }
        else if (wf <= 0.0) { wf_c = 0.0;         wi_c = s_l / A_ll_s; }
        else                { wf_c = wf;          wi_c = wi; }
        const bool do_update = (s_l * AJJ_s - AJl_ * SJ) > 0.0;

        int mode;
        if (do_update) {
            mode = 1;
            const double nSJ = wf_c * SJ + wi_c * s_l;
            AJJ = wf_c * wf_c * AJJ + 2.0 * wf_c * wi_c * AJl_ + wi_c * wi_c * A_ll;
            SJ = nSJ;
        } else {
            mode = 0;
        }

        if (tid == 0) {
            out[i + 1] = (float)((0.5 * trSvv - SJ + 0.5 * AJJ) * c_inv);
            out[SEQ + i + 1] = mode ? 1.f : 0.f;
        }

        // dec_{i+1} now in registers on every thread — no broadcast needed
        dwf = (float)wf_c; dwi = (float)wi_c; dmode = mode;
        vcur = vnext; vnext = vn2; vn2 = vnew;
    }

    // ---- epilogue: apply final update (dec_{SEQ-1}) and store J ----
    {
        const int p = (SEQ - 1) % 3;
        const float4* k4 = (const float4*)&ring[p][2][c0s];
        const float4 kk0 = k4[0], kk1 = k4[1], kk2 = k4[2], kk3 = k4[3];
        if (dmode == 2) {
            jr0.x = vcur*kk0.x; jr0.y = vcur*kk0.y; jr0.z = vcur*kk0.z; jr0.w = vcur*kk0.w;
            jr1.x = vcur*kk1.x; jr1.y = vcur*kk1.y; jr1.z = vcur*kk1.z; jr1.w = vcur*kk1.w;
            jr2.x = vcur*kk2.x; jr2.y = vcur*kk2.y; jr2.z = vcur*kk2.z; jr2.w = vcur*kk2.w;
            jr3.x = vcur*kk3.x; jr3.y = vcur*kk3.y; jr3.z = vcur*kk3.z; jr3.w = vcur*kk3.w;
        } else if (dmode == 1) {
            const float wvr = dwi * vcur;
            jr0.x = fmaf(jr0.x, dwf, wvr*kk0.x); jr0.y = fmaf(jr0.y, dwf, wvr*kk0.y);
            jr0.z = fmaf(jr0.z, dwf, wvr*kk0.z); jr0.w = fmaf(jr0.w, dwf, wvr*kk0.w);
            jr1.x = fmaf(jr1.x, dwf, wvr*kk1.x); jr1.y = fmaf(jr1.y, dwf, wvr*kk1.y);
            jr1.z = fmaf(jr1.z, dwf, wvr*kk1.z); jr1.w = fmaf(jr1.w, dwf, wvr*kk1.w);
            jr2.x = fmaf(jr2.x, dwf, wvr*kk2.x); jr2.y = fmaf(jr2.y, dwf, wvr*kk2.y);
            jr2.z = fmaf(jr2.z, dwf, wvr*kk2.z); jr2.w = fmaf(jr2.w, dwf, wvr*kk2.w);
            jr3.x = fmaf(jr3.x, dwf, wvr*kk3.x); jr3.y = fmaf(jr3.y, dwf, wvr*kk3.y);
            jr3.z = fmaf(jr3.z, dwf, wvr*kk3.z); jr3.w = fmaf(jr3.w, dwf, wvr*kk3.w);
        }
        float* jbase = out + 2 * SEQ + (size_t)r * D + cg * 16;
        *(float4*)(jbase + 0)  = jr0;
        *(float4*)(jbase + 4)  = jr1;
        *(float4*)(jbase + 8)  = jr2;
        *(float4*)(jbase + 12) = jr3;
    }
}

extern "C" void kernel_launch(void* const* d_in, const int* in_sizes, int n_in,
                              void* d_out, int out_size, void* d_ws, size_t ws_size,
                              hipStream_t stream) {
    (void)in_sizes; (void)n_in; (void)out_size; (void)ws_size;
    const float* q = (const float*)d_in[0];
    const float* k = (const float*)d_in[1];
    const float* v = (const float*)d_in[2];
    float* out = (float*)d_out;

    float* U      = (float*)d_ws;            // SEQ*D floats (1 MB)
    float* sl     = U + (size_t)SEQ * D;     // SEQ
    float* kqq    = sl + SEQ;                // SEQ
    float* vv     = kqq + SEQ;               // SEQ
    float* kq_adj = vv + SEQ;                // SEQ
    float* vv_adj = kq_adj + SEQ;            // SEQ
    float* kU_adj = vv_adj + SEQ;            // SEQ
    double* invl  = (double*)(kU_adj + SEQ); // SEQ doubles (8B-aligned)

    precompute_kernel<<<SEQ, 256, 0, stream>>>(q, k, v, U, sl, kqq, vv,
                                               kq_adj, vv_adj, kU_adj, invl);
    scan_kernel<<<1, 1024, 0, stream>>>(q, k, v, U, sl, kqq, vv,
                                        kq_adj, vv_adj, kU_adj, invl, out);
}

// Round 10
// 3200.771 us; speedup vs baseline: 1.3730x; 1.3730x over previous
//
#include <hip/hip_runtime.h>

#define SEQ 2048
#define D 128

// ---------------------------------------------------------------------------
// Kernel 1: per-step J-independent quantities (fully parallel), UNNORMALIZED:
//   alpha_i  = k_s . q_i      (i <= s)
//   kqq[s]   = sum alpha_i^2          = l * (k^T Sqq_l k)
//   sl[s]    = sum alpha_i (v_s.v_i)  = l * (k^T Sqv_l v)
//   vv[s]    = v_s . v_s
//   U[s][c]  = sum_i q_i[c] alpha_i   = l * (Sqq_l k)[c]
//   invl[s]  = 1.0 / l   (fp64, for cost rescale)
// Adjacency scalars (for the scan's lagged-matvec corrections):
//   kq_adj[s] = k_{s-1} . q_s ; vv_adj[s] = v_s . v_{s-1} ; kU_adj[s] = k_{s-1} . U_s
// ---------------------------------------------------------------------------
__global__ __launch_bounds__(256) void precompute_kernel(
    const float* __restrict__ q, const float* __restrict__ k, const float* __restrict__ v,
    float* __restrict__ U, float* __restrict__ sl, float* __restrict__ kqq,
    float* __restrict__ vv, float* __restrict__ kq_adj, float* __restrict__ vv_adj,
    float* __restrict__ kU_adj, double* __restrict__ invl)
{
    const int s = blockIdx.x;
    const int tid = threadIdx.x;

    __shared__ float ks[D];
    __shared__ float vs[D];
    __shared__ float alpha[SEQ];
    __shared__ float red[8];
    __shared__ float upart[256];

    if (tid < D) ks[tid] = k[s * D + tid];
    else if (tid < 2 * D) vs[tid - D] = v[s * D + (tid - D)];
    __syncthreads();

    float p_a2 = 0.f, p_ab = 0.f;
    for (int i = tid; i <= s; i += 256) {
        const float4* qr = (const float4*)(q + (size_t)i * D);
        const float4* vr = (const float4*)(v + (size_t)i * D);
        float a = 0.f, b = 0.f;
#pragma unroll
        for (int j = 0; j < D / 4; ++j) {
            float4 q4 = qr[j];
            float4 v4 = vr[j];
            a += q4.x * ks[4 * j + 0] + q4.y * ks[4 * j + 1] + q4.z * ks[4 * j + 2] + q4.w * ks[4 * j + 3];
            b += v4.x * vs[4 * j + 0] + v4.y * vs[4 * j + 1] + v4.z * vs[4 * j + 2] + v4.w * vs[4 * j + 3];
        }
        alpha[i] = a;
        p_a2 += a * a;
        p_ab += a * b;
        if (i == s) vv[s] = b;  // v_s . v_s
    }
#pragma unroll
    for (int off = 1; off < 64; off <<= 1) {
        p_a2 += __shfl_xor(p_a2, off);
        p_ab += __shfl_xor(p_ab, off);
    }
    const int wid = tid >> 6;
    if ((tid & 63) == 0) { red[wid] = p_a2; red[4 + wid] = p_ab; }
    __syncthreads();  // also makes alpha[] visible to everyone
    if (tid == 0) {
        kqq[s] = red[0] + red[1] + red[2] + red[3];
        sl[s]  = red[4] + red[5] + red[6] + red[7];
        invl[s] = 1.0 / (double)(s + 1);
    }

    // ---- adjacency dots: wave 0 -> kq_adj[s+1], wave 1 -> vv_adj[s] ----
    if (tid < 64) {
        if (s + 1 < SEQ) {
            float p2 = ks[tid] * q[(size_t)(s + 1) * D + tid]
                     + ks[tid + 64] * q[(size_t)(s + 1) * D + 64 + tid];
#pragma unroll
            for (int off = 1; off < 64; off <<= 1) p2 += __shfl_xor(p2, off);
            if (tid == 0) kq_adj[s + 1] = p2;
        }
        if (s == 0 && tid == 0) { kq_adj[0] = 0.f; kU_adj[0] = 0.f; vv_adj[0] = 0.f; }
    } else if (tid < 128 && s > 0) {
        const int t2 = tid - 64;
        float p2 = vs[t2] * v[(size_t)(s - 1) * D + t2]
                 + vs[t2 + 64] * v[(size_t)(s - 1) * D + 64 + t2];
#pragma unroll
        for (int off = 1; off < 64; off <<= 1) p2 += __shfl_xor(p2, off);
        if (t2 == 0) vv_adj[s] = p2;
    }

    // pass 2: U[s][c] = sum_i q[i][c] * alpha[i], i parity-split over h,
    // 4 independent accumulators to break the dependent fma chain
    const int c = tid & (D - 1);
    const int h = tid >> 7;  // 0 or 1
    float a0 = 0.f, a1 = 0.f, a2 = 0.f, a3 = 0.f;
    int i = h;
    for (; i + 6 <= s; i += 8) {
        a0 = fmaf(q[(size_t)(i    ) * D + c], alpha[i    ], a0);
        a1 = fmaf(q[(size_t)(i + 2) * D + c], alpha[i + 2], a1);
        a2 = fmaf(q[(size_t)(i + 4) * D + c], alpha[i + 4], a2);
        a3 = fmaf(q[(size_t)(i + 6) * D + c], alpha[i + 6], a3);
    }
    for (; i <= s; i += 2) a0 = fmaf(q[(size_t)i * D + c], alpha[i], a0);
    upart[tid] = (a0 + a1) + (a2 + a3);
    __syncthreads();

    // U store + kU_adj[s] = k_{s-1}.U_s
    float kup = 0.f;
    if (tid < D) {
        const float uv = upart[tid] + upart[tid + D];
        U[(size_t)s * D + tid] = uv;
        if (s > 0) kup = uv * k[(size_t)(s - 1) * D + tid];
    }
#pragma unroll
    for (int off = 1; off < 64; off <<= 1) kup += __shfl_xor(kup, off);
    if (tid == 0)  red[0] = kup;
    if (tid == 64) red[1] = kup;
    __syncthreads();
    if (s > 0 && tid == 0) kU_adj[s] = red[0] + red[1];
}

// ---------------------------------------------------------------------------
// DPP helpers (correctness verified in R7: absmax unchanged):
//   0xB1 quad_perm xor1 | 0x4E quad_perm xor2 | 0x141 ROW_HALF_MIRROR |
//   0x140 ROW_MIRROR | 0x142 ROW_BCAST15 | 0x143 ROW_BCAST31
// ---------------------------------------------------------------------------
#define DPP_ADD(x, ctrl) \
    ((x) + __int_as_float(__builtin_amdgcn_update_dpp(0, __float_as_int(x), (ctrl), 0xf, 0xf, true)))
// sum over each consecutive group of 8 lanes; result in all 8 lanes
#define COMBINE8(x) do { x = DPP_ADD(x, 0xB1); x = DPP_ADD(x, 0x4E); x = DPP_ADD(x, 0x141); } while (0)
// sum over all 64 lanes; result valid in LANE 63 only
#define REDUCE64(x) do { x = DPP_ADD(x, 0xB1); x = DPP_ADD(x, 0x4E); x = DPP_ADD(x, 0x141); \
                         x = DPP_ADD(x, 0x140); x = DPP_ADD(x, 0x142); x = DPP_ADD(x, 0x143); } while (0)
// sum over each row of 16 lanes; result in ALL lanes of the row
#define REDUCE16(x) do { x = DPP_ADD(x, 0xB1); x = DPP_ADD(x, 0x4E); x = DPP_ADD(x, 0x141); \
                         x = DPP_ADD(x, 0x140); } while (0)

// ---------------------------------------------------------------------------
// Kernel 2: sequential scan, 1024 threads (16 waves, 4/SIMD).
// ROUND-10 = R8 skeleton (lagged matvec, wave0-exclusive fp64 chain, 2
// barriers, 16-float-J no-spill partition) + R9 swizzled conflict-free ring
// + R7 DPP reductions (VALU-latency, not LDS-latency). Only Yq^2 needs the
// pre-combine (x8 copies, exact *0.125 in fp64); r1/r3/r4 are linear in raw
// partials -> straight REDUCE64. J-update moved BETWEEN B1 and B2 so 15
// waves apply it concurrently with wave0's chain (ring[p] stays valid:
// overwritten only at iter i+1 pre-B1, i.e. after B2(i)).
// ---------------------------------------------------------------------------
__global__ __launch_bounds__(1024, 4) void scan_kernel(
    const float* __restrict__ q, const float* __restrict__ k, const float* __restrict__ v,
    const float* __restrict__ U, const float* __restrict__ sl_arr,
    const float* __restrict__ kqq_arr, const float* __restrict__ vv_arr,
    const float* __restrict__ kq_adj, const float* __restrict__ vv_adj,
    const float* __restrict__ kU_adj, const double* __restrict__ invl_arr,
    float* __restrict__ out)  // [0,2048) costs | [2048,4096) updated | [4096,...) J
{
    const int tid  = threadIdx.x;
    const int lane = tid & 63;
    const int w    = __builtin_amdgcn_readfirstlane(tid >> 6);  // 0..15
    const int r    = tid >> 3;        // my row 0..127
    const int cg   = tid & 7;
    const int c0s  = cg * 20;         // swizzled LDS chunk offset

    float4 jr0 = make_float4(0.f, 0.f, 0.f, 0.f);
    float4 jr1 = jr0, jr2 = jr0, jr3 = jr0;

    __shared__ float ring[3][3][160];                 // [phase][q,u,k][swizzled]
    __shared__ __align__(16) float wred[2][16][4];    // [parity][wave][r1,r2,r3,r4]
    __shared__ __align__(16) float decLDS[4];

    const bool stager = tid < 384;
    const int  which  = tid >> 7;     // 0:q 1:u 2:k (for tid<384)
    const int  sidx   = tid & 127;
    const int  widx   = ((sidx >> 4) * 20) + (sidx & 15);  // swizzled write idx

    // ---- prologue: stage phases 0,1; gstage holds phase-2 data ----
    // invariant: phase j holds q_{j+1}, u_{j+1}, k_j
    float gstage = 0.f;
    if (stager) {
        if (which == 0) {
            ring[0][0][widx] = q[(size_t)1 * D + sidx];
            ring[1][0][widx] = q[(size_t)2 * D + sidx];
            gstage = q[(size_t)3 * D + sidx];
        } else if (which == 1) {
            ring[0][1][widx] = U[(size_t)1 * D + sidx];
            ring[1][1][widx] = U[(size_t)2 * D + sidx];
            gstage = U[(size_t)3 * D + sidx];
        } else {
            ring[0][2][widx] = k[sidx];
            ring[1][2][widx] = k[(size_t)1 * D + sidx];
            gstage = k[(size_t)2 * D + sidx];
        }
    }
    float vcur = v[r], vnext = v[(size_t)D + r], vn2 = v[(size_t)2 * D + r];

    // dec_0 is always mode 2 (first step: J_0 = v_0 k_0^T)
    float dwf = 0.f, dwi = 1.f;
    int dmode = 2;

    double SJ = 0.0, AJJ = 0.0, trSvv = 0.0;  // live on wave 0 only
    if (w == 0) {
        const double sl0 = (double)sl_arr[0];
        const double kq0 = (double)kqq_arr[0];
        const double vv0 = (double)vv_arr[0];
        trSvv = vv0;
        SJ  = sl0;
        AJJ = vv0 * kq0;
        if (lane == 0) {
            out[0] = (float)((0.5 * trSvv - SJ + 0.5 * AJJ) * invl_arr[0]);
            out[SEQ] = 1.f;
        }
    }
    __syncthreads();

    for (int i = 0; i < SEQ - 1; ++i) {
        const int p   = i % 3;
        const int pw  = (i + 2) % 3;
        const int par = i & 1;

        // ---- wave0: chain scalars (uniform s_loads, issued early) ----
        float c_sl = 0.f, c_kq = 0.f, c_vv = 0.f, c_kqa = 0.f, c_vva = 0.f,
              c_vvp = 0.f, c_kua = 0.f;
        double c_inv = 0.0;
        if (w == 0) {
            c_sl  = sl_arr[i + 1];  c_kq  = kqq_arr[i + 1]; c_vv  = vv_arr[i + 1];
            c_kqa = kq_adj[i + 1];  c_vva = vv_adj[i + 1];  c_vvp = vv_arr[i];
            c_kua = kU_adj[i + 1];  c_inv = invl_arr[i + 1];
        }

        // ---- ring reads: q_{i+1}, u_{i+1} (dot operands), k_i (update) ----
        const float4* q4 = (const float4*)&ring[p][0][c0s];
        const float4* u4 = (const float4*)&ring[p][1][c0s];
        const float4* k4 = (const float4*)&ring[p][2][c0s];
        const float4 qa = q4[0], qb = q4[1], qc = q4[2], qd = q4[3];
        const float4 ua = u4[0], ub = u4[1], uc = u4[2], ud = u4[3];
        const float4 kk0 = k4[0], kk1 = k4[1], kk2 = k4[2], kk3 = k4[3];

        // ---- dot: Y' = J_{i-1} q_{i+1}, W' = J_{i-1} u_{i+1} ----
        float pa = jr0.x * qa.x, pb = jr2.x * qc.x;
        pa = fmaf(jr0.y, qa.y, pa); pb = fmaf(jr2.y, qc.y, pb);
        pa = fmaf(jr0.z, qa.z, pa); pb = fmaf(jr2.z, qc.z, pb);
        pa = fmaf(jr0.w, qa.w, pa); pb = fmaf(jr2.w, qc.w, pb);
        pa = fmaf(jr1.x, qb.x, pa); pb = fmaf(jr3.x, qd.x, pb);
        pa = fmaf(jr1.y, qb.y, pa); pb = fmaf(jr3.y, qd.y, pb);
        pa = fmaf(jr1.z, qb.z, pa); pb = fmaf(jr3.z, qd.z, pb);
        pa = fmaf(jr1.w, qb.w, pa); pb = fmaf(jr3.w, qd.w, pb);
        const float pq = pa + pb;
        float va_ = jr0.x * ua.x, vb_ = jr2.x * uc.x;
        va_ = fmaf(jr0.y, ua.y, va_); vb_ = fmaf(jr2.y, uc.y, vb_);
        va_ = fmaf(jr0.z, ua.z, va_); vb_ = fmaf(jr2.z, uc.z, vb_);
        va_ = fmaf(jr0.w, ua.w, va_); vb_ = fmaf(jr2.w, uc.w, vb_);
        va_ = fmaf(jr1.x, ub.x, va_); vb_ = fmaf(jr3.x, ud.x, vb_);
        va_ = fmaf(jr1.y, ub.y, va_); vb_ = fmaf(jr3.y, ud.y, vb_);
        va_ = fmaf(jr1.z, ub.z, va_); vb_ = fmaf(jr3.z, ud.z, vb_);
        va_ = fmaf(jr1.w, ub.w, va_); vb_ = fmaf(jr3.w, ud.w, vb_);
        const float pu = va_ + vb_;

        // ---- step scalars: r1/r3/r4 linear in raw partials; r2 needs Yq ----
        float z1 = vnext * pq;     // -> v_{i+1}.Y'
        float z3 = vcur  * pq;     // -> v_i.Y'
        float z4 = vnext * pu;     // -> v_{i+1}.W'
        float yq = pq;
        COMBINE8(yq);              // full (Y')_r on all 8 lanes of row r
        float z2 = yq * yq;        // counted 8x -> exact *0.125 in fp64
        REDUCE64(z1);
        REDUCE64(z2);
        REDUCE64(z3);
        REDUCE64(z4);
        if (lane == 63) *(float4*)&wred[par][w][0] = make_float4(z1, z2, z3, z4);

        // ---- staging write (phase i+2) + next prefetches ----
        if (stager) {
            ring[pw][which][widx] = gstage;
            const int tq = (i + 4 < SEQ) ? i + 4 : SEQ - 1;
            const int tk = (i + 3 < SEQ) ? i + 3 : SEQ - 1;
            gstage = (which == 0) ? q[(size_t)tq * D + sidx]
                   : (which == 1) ? U[(size_t)tq * D + sidx]
                                  : k[(size_t)tk * D + sidx];
        }
        const int tv = (i + 3 < SEQ) ? i + 3 : SEQ - 1;
        const float vnew = v[(size_t)tv * D + r];

        __syncthreads();  // B1

        // ---- wave0: issue wred read first (latency hidden by J update) ----
        float4 ww;
        if (w == 0) ww = *(const float4*)&wred[par][lane & 15][0];

        // ---- ALL waves: update J_{i-1} -> J_i with dec_i (overlaps chain) --
        if (dmode == 2) {
            jr0.x = vcur*kk0.x; jr0.y = vcur*kk0.y; jr0.z = vcur*kk0.z; jr0.w = vcur*kk0.w;
            jr1.x = vcur*kk1.x; jr1.y = vcur*kk1.y; jr1.z = vcur*kk1.z; jr1.w = vcur*kk1.w;
            jr2.x = vcur*kk2.x; jr2.y = vcur*kk2.y; jr2.z = vcur*kk2.z; jr2.w = vcur*kk2.w;
            jr3.x = vcur*kk3.x; jr3.y = vcur*kk3.y; jr3.z = vcur*kk3.z; jr3.w = vcur*kk3.w;
        } else if (dmode == 1) {
            const float wvr = dwi * vcur;
            jr0.x = fmaf(jr0.x, dwf, wvr*kk0.x); jr0.y = fmaf(jr0.y, dwf, wvr*kk0.y);
            jr0.z = fmaf(jr0.z, dwf, wvr*kk0.z); jr0.w = fmaf(jr0.w, dwf, wvr*kk0.w);
            jr1.x = fmaf(jr1.x, dwf, wvr*kk1.x); jr1.y = fmaf(jr1.y, dwf, wvr*kk1.y);
            jr1.z = fmaf(jr1.z, dwf, wvr*kk1.z); jr1.w = fmaf(jr1.w, dwf, wvr*kk1.w);
            jr2.x = fmaf(jr2.x, dwf, wvr*kk2.x); jr2.y = fmaf(jr2.y, dwf, wvr*kk2.y);
            jr2.z = fmaf(jr2.z, dwf, wvr*kk2.z); jr2.w = fmaf(jr2.w, dwf, wvr*kk2.w);
            jr3.x = fmaf(jr3.x, dwf, wvr*kk3.x); jr3.y = fmaf(jr3.y, dwf, wvr*kk3.y);
            jr3.z = fmaf(jr3.z, dwf, wvr*kk3.z); jr3.w = fmaf(jr3.w, dwf, wvr*kk3.w);
        }

        // ---- wave0: cross-wave reduce (DPP) + fp64 chain ----
        if (w == 0) {
            REDUCE16(ww.x);
            REDUCE16(ww.y);
            REDUCE16(ww.z);
            REDUCE16(ww.w);

            double a, b;
            if (dmode == 2)      { a = 0.0; b = 1.0; }
            else if (dmode == 1) { a = (double)dwf; b = (double)dwi; }
            else                 { a = 1.0; b = 0.0; }
            const double kqa = (double)c_kqa, vva = (double)c_vva;
            const double vvp = (double)c_vvp, kua = (double)c_kua;
            const double r1 = (double)ww.x, r2 = (double)ww.y * 0.125;
            const double r3 = (double)ww.z, r4 = (double)ww.w;
            const double Jqv  = a * r1 + b * (kqa * vva);
            const double Jq2  = a * a * r2 + 2.0 * a * b * kqa * r3 + b * b * kqa * kqa * vvp;
            const double AJl_ = a * r4 + b * kua * vva;

            trSvv += (double)c_vv;
            SJ    += Jqv;
            AJJ   += Jq2;
            const double s_l  = (double)c_sl;
            const double A_ll = (double)c_vv * (double)c_kq;
            const double AJJ_s  = (AJJ == 0.0)  ? 1.0 : AJJ;
            const double A_ll_s = (A_ll == 0.0) ? 1.0 : A_ll;
            const double denom   = AJJ * A_ll - AJl_ * AJl_;
            const double denom_s = (denom == 0.0) ? 1.0 : denom;
            const double rden = 1.0 / denom_s;
            const double wf = (A_ll * SJ - AJl_ * s_l) * rden;
            const double wi = (AJJ * s_l - AJl_ * SJ) * rden;
            double wf_c, wi_c;
            if (wi <= 0.0)      { wf_c = SJ / AJJ_s;  wi_c = 0.0; }
            else if (wf <= 0.0) { wf_c = 0.0;         wi_c = s_l / A_ll_s; }
            else                { wf_c = wf;          wi_c = wi; }
            const bool do_update = (s_l * AJJ_s - AJl_ * SJ) > 0.0;

            int mode;
            if (do_update) {
                mode = 1;
                const double nSJ = wf_c * SJ + wi_c * s_l;
                AJJ = wf_c * wf_c * AJJ + 2.0 * wf_c * wi_c * AJl_ + wi_c * wi_c * A_ll;
                SJ = nSJ;
            } else {
                mode = 0;
            }

            if (lane == 0) {
                out[i + 1] = (float)((0.5 * trSvv - SJ + 0.5 * AJJ) * c_inv);
                out[SEQ + i + 1] = mode ? 1.f : 0.f;
                *(float4*)decLDS = make_float4((float)wf_c, (float)wi_c, (float)mode, 0.f);
            }
        }

        __syncthreads();  // B2

        const float4 df = *(const float4*)decLDS;
        dwf = df.x; dwi = df.y; dmode = (int)df.z;
        vcur = vnext; vnext = vn2; vn2 = vnew;
    }

    // ---- epilogue: apply final update (dec_{SEQ-1}) and store J ----
    {
        const int p = (SEQ - 1) % 3;
        const float4* k4 = (const float4*)&ring[p][2][c0s];
        const float4 kk0 = k4[0], kk1 = k4[1], kk2 = k4[2], kk3 = k4[3];
        if (dmode == 2) {
            jr0.x = vcur*kk0.x; jr0.y = vcur*kk0.y; jr0.z = vcur*kk0.z; jr0.w = vcur*kk0.w;
            jr1.x = vcur*kk1.x; jr1.y = vcur*kk1.y; jr1.z = vcur*kk1.z; jr1.w = vcur*kk1.w;
            jr2.x = vcur*kk2.x; jr2.y = vcur*kk2.y; jr2.z = vcur*kk2.z; jr2.w = vcur*kk2.w;
            jr3.x = vcur*kk3.x; jr3.y = vcur*kk3.y; jr3.z = vcur*kk3.z; jr3.w = vcur*kk3.w;
        } else if (dmode == 1) {
            const float wvr = dwi * vcur;
            jr0.x = fmaf(jr0.x, dwf, wvr*kk0.x); jr0.y = fmaf(jr0.y, dwf, wvr*kk0.y);
            jr0.z = fmaf(jr0.z, dwf, wvr*kk0.z); jr0.w = fmaf(jr0.w, dwf, wvr*kk0.w);
            jr1.x = fmaf(jr1.x, dwf, wvr*kk1.x); jr1.y = fmaf(jr1.y, dwf, wvr*kk1.y);
            jr1.z = fmaf(jr1.z, dwf, wvr*kk1.z); jr1.w = fmaf(jr1.w, dwf, wvr*kk1.w);
            jr2.x = fmaf(jr2.x, dwf, wvr*kk2.x); jr2.y = fmaf(jr2.y, dwf, wvr*kk2.y);
            jr2.z = fmaf(jr2.z, dwf, wvr*kk2.z); jr2.w = fmaf(jr2.w, dwf, wvr*kk2.w);
            jr3.x = fmaf(jr3.x, dwf, wvr*kk3.x); jr3.y = fmaf(jr3.y, dwf, wvr*kk3.y);
            jr3.z = fmaf(jr3.z, dwf, wvr*kk3.z); jr3.w = fmaf(jr3.w, dwf, wvr*kk3.w);
        }
        float* jbase = out + 2 * SEQ + (size_t)r * D + cg * 16;
        *(float4*)(jbase + 0)  = jr0;
        *(float4*)(jbase + 4)  = jr1;
        *(float4*)(jbase + 8)  = jr2;
        *(float4*)(jbase + 12) = jr3;
    }
}

extern "C" void kernel_launch(void* const* d_in, const int* in_sizes, int n_in,
                              void* d_out, int out_size, void* d_ws, size_t ws_size,
                              hipStream_t stream) {
    (void)in_sizes; (void)n_in; (void)out_size; (void)ws_size;
    const float* q = (const float*)d_in[0];
    const float* k = (const float*)d_in[1];
    const float* v = (const float*)d_in[2];
    float* out = (float*)d_out;

    float* U      = (float*)d_ws;            // SEQ*D floats (1 MB)
    float* sl     = U + (size_t)SEQ * D;     // SEQ
    float* kqq    = sl + SEQ;                // SEQ
    float* vv     = kqq + SEQ;               // SEQ
    float* kq_adj = vv + SEQ;                // SEQ
    float* vv_adj = kq_adj + SEQ;            // SEQ
    float* kU_adj = vv_adj + SEQ;            // SEQ
    double* invl  = (double*)(kU_adj + SEQ); // SEQ doubles (8B-aligned)

    precompute_kernel<<<SEQ, 256, 0, stream>>>(q, k, v, U, sl, kqq, vv,
                                               kq_adj, vv_adj, kU_adj, invl);
    scan_kernel<<<1, 1024, 0, stream>>>(q, k, v, U, sl, kqq, vv,
                                        kq_adj, vv_adj, kU_adj, invl, out);
}

// Round 11
// 2656.919 us; speedup vs baseline: 1.6540x; 1.2047x over previous
//
#include <hip/hip_runtime.h>

#define SEQ 2048
#define D 128

// ---------------------------------------------------------------------------
// Kernel 1: per-step J-independent quantities (fully parallel), UNNORMALIZED:
//   alpha_i  = k_s . q_i      (i <= s)
//   kqq[s]   = sum alpha_i^2          = l * (k^T Sqq_l k)
//   sl[s]    = sum alpha_i (v_s.v_i)  = l * (k^T Sqv_l v)
//   vv[s]    = v_s . v_s
//   U[s][c]  = sum_i q_i[c] alpha_i   = l * (Sqq_l k)[c]
//   invl[s]  = 1.0 / l   (fp64, for cost rescale)
// Adjacency scalars (for the scan's lagged-matvec corrections):
//   kq_adj[s] = k_{s-1} . q_s ; vv_adj[s] = v_s . v_{s-1} ; kU_adj[s] = k_{s-1} . U_s
// ---------------------------------------------------------------------------
__global__ __launch_bounds__(256) void precompute_kernel(
    const float* __restrict__ q, const float* __restrict__ k, const float* __restrict__ v,
    float* __restrict__ U, float* __restrict__ sl, float* __restrict__ kqq,
    float* __restrict__ vv, float* __restrict__ kq_adj, float* __restrict__ vv_adj,
    float* __restrict__ kU_adj, double* __restrict__ invl)
{
    const int s = blockIdx.x;
    const int tid = threadIdx.x;

    __shared__ float ks[D];
    __shared__ float vs[D];
    __shared__ float alpha[SEQ];
    __shared__ float red[8];
    __shared__ float upart[256];

    if (tid < D) ks[tid] = k[s * D + tid];
    else if (tid < 2 * D) vs[tid - D] = v[s * D + (tid - D)];
    __syncthreads();

    float p_a2 = 0.f, p_ab = 0.f;
    for (int i = tid; i <= s; i += 256) {
        const float4* qr = (const float4*)(q + (size_t)i * D);
        const float4* vr = (const float4*)(v + (size_t)i * D);
        float a = 0.f, b = 0.f;
#pragma unroll
        for (int j = 0; j < D / 4; ++j) {
            float4 q4 = qr[j];
            float4 v4 = vr[j];
            a += q4.x * ks[4 * j + 0] + q4.y * ks[4 * j + 1] + q4.z * ks[4 * j + 2] + q4.w * ks[4 * j + 3];
            b += v4.x * vs[4 * j + 0] + v4.y * vs[4 * j + 1] + v4.z * vs[4 * j + 2] + v4.w * vs[4 * j + 3];
        }
        alpha[i] = a;
        p_a2 += a * a;
        p_ab += a * b;
        if (i == s) vv[s] = b;  // v_s . v_s
    }
#pragma unroll
    for (int off = 1; off < 64; off <<= 1) {
        p_a2 += __shfl_xor(p_a2, off);
        p_ab += __shfl_xor(p_ab, off);
    }
    const int wid = tid >> 6;
    if ((tid & 63) == 0) { red[wid] = p_a2; red[4 + wid] = p_ab; }
    __syncthreads();  // also makes alpha[] visible to everyone
    if (tid == 0) {
        kqq[s] = red[0] + red[1] + red[2] + red[3];
        sl[s]  = red[4] + red[5] + red[6] + red[7];
        invl[s] = 1.0 / (double)(s + 1);
    }

    // ---- adjacency dots: wave 0 -> kq_adj[s+1], wave 1 -> vv_adj[s] ----
    if (tid < 64) {
        if (s + 1 < SEQ) {
            float p2 = ks[tid] * q[(size_t)(s + 1) * D + tid]
                     + ks[tid + 64] * q[(size_t)(s + 1) * D + 64 + tid];
#pragma unroll
            for (int off = 1; off < 64; off <<= 1) p2 += __shfl_xor(p2, off);
            if (tid == 0) kq_adj[s + 1] = p2;
        }
        if (s == 0 && tid == 0) { kq_adj[0] = 0.f; kU_adj[0] = 0.f; vv_adj[0] = 0.f; }
    } else if (tid < 128 && s > 0) {
        const int t2 = tid - 64;
        float p2 = vs[t2] * v[(size_t)(s - 1) * D + t2]
                 + vs[t2 + 64] * v[(size_t)(s - 1) * D + 64 + t2];
#pragma unroll
        for (int off = 1; off < 64; off <<= 1) p2 += __shfl_xor(p2, off);
        if (t2 == 0) vv_adj[s] = p2;
    }

    // pass 2: U[s][c] = sum_i q[i][c] * alpha[i], i parity-split over h,
    // 4 independent accumulators to break the dependent fma chain
    const int c = tid & (D - 1);
    const int h = tid >> 7;  // 0 or 1
    float a0 = 0.f, a1 = 0.f, a2 = 0.f, a3 = 0.f;
    int i = h;
    for (; i + 6 <= s; i += 8) {
        a0 = fmaf(q[(size_t)(i    ) * D + c], alpha[i    ], a0);
        a1 = fmaf(q[(size_t)(i + 2) * D + c], alpha[i + 2], a1);
        a2 = fmaf(q[(size_t)(i + 4) * D + c], alpha[i + 4], a2);
        a3 = fmaf(q[(size_t)(i + 6) * D + c], alpha[i + 6], a3);
    }
    for (; i <= s; i += 2) a0 = fmaf(q[(size_t)i * D + c], alpha[i], a0);
    upart[tid] = (a0 + a1) + (a2 + a3);
    __syncthreads();

    // U store + kU_adj[s] = k_{s-1}.U_s
    float kup = 0.f;
    if (tid < D) {
        const float uv = upart[tid] + upart[tid + D];
        U[(size_t)s * D + tid] = uv;
        if (s > 0) kup = uv * k[(size_t)(s - 1) * D + tid];
    }
#pragma unroll
    for (int off = 1; off < 64; off <<= 1) kup += __shfl_xor(kup, off);
    if (tid == 0)  red[0] = kup;
    if (tid == 64) red[1] = kup;
    __syncthreads();
    if (s > 0 && tid == 0) kU_adj[s] = red[0] + red[1];
}

// ---------------------------------------------------------------------------
// DPP helpers (R7/R10-verified):
//   0xB1 quad_perm xor1 | 0x4E quad_perm xor2 | 0x141 ROW_HALF_MIRROR |
//   0x140 ROW_MIRROR | 0x142 ROW_BCAST15 | 0x143 ROW_BCAST31
// ---------------------------------------------------------------------------
#define DPP_ADD(x, ctrl) \
    ((x) + __int_as_float(__builtin_amdgcn_update_dpp(0, __float_as_int(x), (ctrl), 0xf, 0xf, true)))
// sum within each 8-lane group; result in all 8 lanes
#define COMBINE8(x) do { x = DPP_ADD(x, 0xB1); x = DPP_ADD(x, 0x4E); x = DPP_ADD(x, 0x141); } while (0)
// after COMBINE8 (value constant per 8-group): sum the 8 groups; lane 63 holds total
#define TAIL3(x)    do { x = DPP_ADD(x, 0x140); x = DPP_ADD(x, 0x142); x = DPP_ADD(x, 0x143); } while (0)
// sum over each row of 16 lanes; result in ALL lanes of the row
#define REDUCE16(x) do { x = DPP_ADD(x, 0xB1); x = DPP_ADD(x, 0x4E); x = DPP_ADD(x, 0x141); \
                         x = DPP_ADD(x, 0x140); } while (0)

#define UPDATE_J(MODE, WF, WI)                                                            \
    if ((MODE) == 2) {                                                                    \
        jr0.x = vcur*kk0.x; jr0.y = vcur*kk0.y; jr0.z = vcur*kk0.z; jr0.w = vcur*kk0.w;   \
        jr1.x = vcur*kk1.x; jr1.y = vcur*kk1.y; jr1.z = vcur*kk1.z; jr1.w = vcur*kk1.w;   \
        jr2.x = vcur*kk2.x; jr2.y = vcur*kk2.y; jr2.z = vcur*kk2.z; jr2.w = vcur*kk2.w;   \
        jr3.x = vcur*kk3.x; jr3.y = vcur*kk3.y; jr3.z = vcur*kk3.z; jr3.w = vcur*kk3.w;   \
    } else if ((MODE) == 1) {                                                             \
        const float wvr = (WI) * vcur;                                                    \
        jr0.x = fmaf(jr0.x, (WF), wvr*kk0.x); jr0.y = fmaf(jr0.y, (WF), wvr*kk0.y);       \
        jr0.z = fmaf(jr0.z, (WF), wvr*kk0.z); jr0.w = fmaf(jr0.w, (WF), wvr*kk0.w);       \
        jr1.x = fmaf(jr1.x, (WF), wvr*kk1.x); jr1.y = fmaf(jr1.y, (WF), wvr*kk1.y);       \
        jr1.z = fmaf(jr1.z, (WF), wvr*kk1.z); jr1.w = fmaf(jr1.w, (WF), wvr*kk1.w);       \
        jr2.x = fmaf(jr2.x, (WF), wvr*kk2.x); jr2.y = fmaf(jr2.y, (WF), wvr*kk2.y);       \
        jr2.z = fmaf(jr2.z, (WF), wvr*kk2.z); jr2.w = fmaf(jr2.w, (WF), wvr*kk2.w);       \
        jr3.x = fmaf(jr3.x, (WF), wvr*kk3.x); jr3.y = fmaf(jr3.y, (WF), wvr*kk3.y);       \
        jr3.z = fmaf(jr3.z, (WF), wvr*kk3.z); jr3.w = fmaf(jr3.w, (WF), wvr*kk3.w);       \
    }

// ---------------------------------------------------------------------------
// Kernel 2: sequential scan, 1024 threads (16 waves, 4/SIMD).
// ROUND-11 = R10 minus B2: ONE barrier per step.
//   Parity analysis: wave0 writes dec_{i+1} post-B1(i); readers consume it
//   post-B1(i+1) -> already barrier-separated. decLDS[2] parity slots (like
//   wred[2]) make the overwrite safe. After their update, waves 1..15 run
//   the NEXT dot concurrently with wave0's chain — the chain is off the
//   group critical path. Stagers moved to waves 6..11 (wave0 carries no
//   staging). Reductions: COMBINE8 both partials, then 3-level tails only
//   (18 DPP levels vs 27); all 4 scalars x8-counted -> *0.125 in fp64.
//   Wave0 updates J from registers (no dec LDS read), interleaved with the
//   wred ds_read latency. Epilogue: final barrier + dec_{SEQ-1} from LDS.
// ---------------------------------------------------------------------------
__global__ __launch_bounds__(1024, 4) void scan_kernel(
    const float* __restrict__ q, const float* __restrict__ k, const float* __restrict__ v,
    const float* __restrict__ U, const float* __restrict__ sl_arr,
    const float* __restrict__ kqq_arr, const float* __restrict__ vv_arr,
    const float* __restrict__ kq_adj, const float* __restrict__ vv_adj,
    const float* __restrict__ kU_adj, const double* __restrict__ invl_arr,
    float* __restrict__ out)  // [0,2048) costs | [2048,4096) updated | [4096,...) J
{
    const int tid  = threadIdx.x;
    const int lane = tid & 63;
    const int w    = __builtin_amdgcn_readfirstlane(tid >> 6);  // 0..15
    const int r    = tid >> 3;        // my row 0..127
    const int cg   = tid & 7;
    const int c0s  = cg * 20;         // swizzled LDS chunk offset

    float4 jr0 = make_float4(0.f, 0.f, 0.f, 0.f);
    float4 jr1 = jr0, jr2 = jr0, jr3 = jr0;

    __shared__ float ring[3][3][160];                 // [phase][q,u,k][swizzled]
    __shared__ __align__(16) float wred[2][16][4];    // [parity][wave][r1,r2,r3,r4]
    __shared__ __align__(16) float decLDS[2][4];      // [parity][wf,wi,mode,-]

    // stagers: waves 6..11 (tid 384..767) — wave0 stays staging-free
    const bool stager = (tid >= 384) && (tid < 768);
    const int  which  = (tid >> 7) - 3;    // 0:q 1:u 2:k (when stager)
    const int  sidx   = tid & 127;
    const int  widx   = ((sidx >> 4) * 20) + (sidx & 15);  // swizzled write idx

    // ---- prologue: stage phases 0,1; gstage holds phase-2 data ----
    // invariant: phase j holds q_{j+1}, u_{j+1}, k_j
    float gstage = 0.f;
    if (stager) {
        if (which == 0) {
            ring[0][0][widx] = q[(size_t)1 * D + sidx];
            ring[1][0][widx] = q[(size_t)2 * D + sidx];
            gstage = q[(size_t)3 * D + sidx];
        } else if (which == 1) {
            ring[0][1][widx] = U[(size_t)1 * D + sidx];
            ring[1][1][widx] = U[(size_t)2 * D + sidx];
            gstage = U[(size_t)3 * D + sidx];
        } else {
            ring[0][2][widx] = k[sidx];
            ring[1][2][widx] = k[(size_t)1 * D + sidx];
            gstage = k[(size_t)2 * D + sidx];
        }
    }
    float vcur = v[r], vnext = v[(size_t)D + r], vn2 = v[(size_t)2 * D + r];

    // dec_0 is always mode 2 (first step: J_0 = v_0 k_0^T)
    float dwf = 0.f, dwi = 1.f;
    int dmode = 2;
    if (tid == 0) { decLDS[0][0] = 0.f; decLDS[0][1] = 1.f; decLDS[0][2] = 2.f; decLDS[0][3] = 0.f; }

    double SJ = 0.0, AJJ = 0.0, trSvv = 0.0;  // live on wave 0 only
    if (w == 0) {
        const double sl0 = (double)sl_arr[0];
        const double kq0 = (double)kqq_arr[0];
        const double vv0 = (double)vv_arr[0];
        trSvv = vv0;
        SJ  = sl0;
        AJJ = vv0 * kq0;
        if (lane == 0) {
            out[0] = (float)((0.5 * trSvv - SJ + 0.5 * AJJ) * invl_arr[0]);
            out[SEQ] = 1.f;
        }
    }
    __syncthreads();

    for (int i = 0; i < SEQ - 1; ++i) {
        const int p    = i % 3;
        const int pw   = (i + 2) % 3;
        const int par  = i & 1;
        const int parn = (i + 1) & 1;

        // ---- wave0: chain scalars (uniform s_loads, issued early) ----
        float c_sl = 0.f, c_kq = 0.f, c_vv = 0.f, c_kqa = 0.f, c_vva = 0.f,
              c_vvp = 0.f, c_kua = 0.f;
        double c_inv = 0.0;
        if (w == 0) {
            c_sl  = sl_arr[i + 1];  c_kq  = kqq_arr[i + 1]; c_vv  = vv_arr[i + 1];
            c_kqa = kq_adj[i + 1];  c_vva = vv_adj[i + 1];  c_vvp = vv_arr[i];
            c_kua = kU_adj[i + 1];  c_inv = invl_arr[i + 1];
        }

        // ---- ring reads: q_{i+1}, u_{i+1} (dot operands), k_i (update) ----
        const float4* q4 = (const float4*)&ring[p][0][c0s];
        const float4* u4 = (const float4*)&ring[p][1][c0s];
        const float4* k4 = (const float4*)&ring[p][2][c0s];
        const float4 qa = q4[0], qb = q4[1], qc = q4[2], qd = q4[3];
        const float4 ua = u4[0], ub = u4[1], uc = u4[2], ud = u4[3];
        const float4 kk0 = k4[0], kk1 = k4[1], kk2 = k4[2], kk3 = k4[3];

        // ---- dot: Y' = J_{i-1} q_{i+1}, W' = J_{i-1} u_{i+1} ----
        float pa = jr0.x * qa.x, pb = jr2.x * qc.x;
        pa = fmaf(jr0.y, qa.y, pa); pb = fmaf(jr2.y, qc.y, pb);
        pa = fmaf(jr0.z, qa.z, pa); pb = fmaf(jr2.z, qc.z, pb);
        pa = fmaf(jr0.w, qa.w, pa); pb = fmaf(jr2.w, qc.w, pb);
        pa = fmaf(jr1.x, qb.x, pa); pb = fmaf(jr3.x, qd.x, pb);
        pa = fmaf(jr1.y, qb.y, pa); pb = fmaf(jr3.y, qd.y, pb);
        pa = fmaf(jr1.z, qb.z, pa); pb = fmaf(jr3.z, qd.z, pb);
        pa = fmaf(jr1.w, qb.w, pa); pb = fmaf(jr3.w, qd.w, pb);
        float Yq = pa + pb;
        float va_ = jr0.x * ua.x, vb_ = jr2.x * uc.x;
        va_ = fmaf(jr0.y, ua.y, va_); vb_ = fmaf(jr2.y, uc.y, vb_);
        va_ = fmaf(jr0.z, ua.z, va_); vb_ = fmaf(jr2.z, uc.z, vb_);
        va_ = fmaf(jr0.w, ua.w, va_); vb_ = fmaf(jr2.w, uc.w, vb_);
        va_ = fmaf(jr1.x, ub.x, va_); vb_ = fmaf(jr3.x, ud.x, vb_);
        va_ = fmaf(jr1.y, ub.y, va_); vb_ = fmaf(jr3.y, ud.y, vb_);
        va_ = fmaf(jr1.z, ub.z, va_); vb_ = fmaf(jr3.z, ud.z, vb_);
        va_ = fmaf(jr1.w, ub.w, va_); vb_ = fmaf(jr3.w, ud.w, vb_);
        float Yw = va_ + vb_;

        // ---- reductions: combine partials first, then 3-level tails ----
        COMBINE8(Yq);              // full (Y')_r on all 8 lanes of row r
        COMBINE8(Yw);
        float z1 = vnext * Yq;     // all x8-counted -> *0.125 in fp64 chain
        float z2 = Yq * Yq;
        float z3 = vcur  * Yq;
        float z4 = vnext * Yw;
        TAIL3(z1);
        TAIL3(z2);
        TAIL3(z3);
        TAIL3(z4);
        if (lane == 63) *(float4*)&wred[par][w][0] = make_float4(z1, z2, z3, z4);

        // ---- staging write (phase i+2) + next prefetches (waves 6-11) ----
        if (stager) {
            ring[pw][which][widx] = gstage;
            const int tq = (i + 4 < SEQ) ? i + 4 : SEQ - 1;
            const int tk = (i + 3 < SEQ) ? i + 3 : SEQ - 1;
            gstage = (which == 0) ? q[(size_t)tq * D + sidx]
                   : (which == 1) ? U[(size_t)tq * D + sidx]
                                  : k[(size_t)tk * D + sidx];
        }
        const int tv = (i + 3 < SEQ) ? i + 3 : SEQ - 1;
        const float vnew = v[(size_t)tv * D + r];

        __syncthreads();  // the ONE barrier

        if (w == 0) {
            // issue wred read first; J-update FMAs interleave with its latency
            float4 ww = *(const float4*)&wred[par][lane & 15][0];
            const float odwf = dwf, odwi = dwi;
            const int   odmode = dmode;
            UPDATE_J(odmode, odwf, odwi)

            REDUCE16(ww.x);
            REDUCE16(ww.y);
            REDUCE16(ww.z);
            REDUCE16(ww.w);

            double a, b;
            if (odmode == 2)      { a = 0.0; b = 1.0; }
            else if (odmode == 1) { a = (double)odwf; b = (double)odwi; }
            else                  { a = 1.0; b = 0.0; }
            const double kqa = (double)c_kqa, vva = (double)c_vva;
            const double vvp = (double)c_vvp, kua = (double)c_kua;
            const double r1 = (double)ww.x * 0.125, r2 = (double)ww.y * 0.125;
            const double r3 = (double)ww.z * 0.125, r4 = (double)ww.w * 0.125;
            const double Jqv  = a * r1 + b * (kqa * vva);
            const double Jq2  = a * a * r2 + 2.0 * a * b * kqa * r3 + b * b * kqa * kqa * vvp;
            const double AJl_ = a * r4 + b * kua * vva;

            trSvv += (double)c_vv;
            SJ    += Jqv;
            AJJ   += Jq2;
            const double s_l  = (double)c_sl;
            const double A_ll = (double)c_vv * (double)c_kq;
            const double AJJ_s  = (AJJ == 0.0)  ? 1.0 : AJJ;
            const double A_ll_s = (A_ll == 0.0) ? 1.0 : A_ll;
            const double denom   = AJJ * A_ll - AJl_ * AJl_;
            const double denom_s = (denom == 0.0) ? 1.0 : denom;
            const double rden = 1.0 / denom_s;
            const double wf = (A_ll * SJ - AJl_ * s_l) * rden;
            const double wi = (AJJ * s_l - AJl_ * SJ) * rden;
            double wf_c, wi_c;
            if (wi <= 0.0)      { wf_c = SJ / AJJ_s;  wi_c = 0.0; }
            else if (wf <= 0.0) { wf_c = 0.0;         wi_c = s_l / A_ll_s; }
            else                { wf_c = wf;          wi_c = wi; }
            const bool do_update = (s_l * AJJ_s - AJl_ * SJ) > 0.0;

            int mode;
            if (do_update) {
                mode = 1;
                const double nSJ = wf_c * SJ + wi_c * s_l;
                AJJ = wf_c * wf_c * AJJ + 2.0 * wf_c * wi_c * AJl_ + wi_c * wi_c * A_ll;
                SJ = nSJ;
            } else {
                mode = 0;
            }

            dwf = (float)wf_c; dwi = (float)wi_c; dmode = mode;
            if (lane == 0) {
                out[i + 1] = (float)((0.5 * trSvv - SJ + 0.5 * AJJ) * c_inv);
                out[SEQ + i + 1] = mode ? 1.f : 0.f;
                *(float4*)&decLDS[parn][0] = make_float4(dwf, dwi, (float)mode, 0.f);
            }
        } else {
            // dec_i written by wave0 in iter i-1 (post-B1(i-1)) -> separated
            // from this read by B1(i)
            const float4 df = *(const float4*)&decLDS[par][0];
            dwf = df.x; dwi = df.y; dmode = (int)df.z;
            UPDATE_J(dmode, dwf, dwi)
        }

        vcur = vnext; vnext = vn2; vn2 = vnew;
    }

    // ---- epilogue: apply final update (dec_{SEQ-1}) and store J ----
    __syncthreads();  // make wave0's decLDS[(SEQ-1)&1] write visible
    {
        const float4 df = *(const float4*)&decLDS[(SEQ - 1) & 1][0];
        const float fwf = df.x, fwi = df.y;
        const int   fmode = (int)df.z;
        const int p = (SEQ - 1) % 3;
        const float4* k4 = (const float4*)&ring[p][2][c0s];
        const float4 kk0 = k4[0], kk1 = k4[1], kk2 = k4[2], kk3 = k4[3];
        UPDATE_J(fmode, fwf, fwi)
        float* jbase = out + 2 * SEQ + (size_t)r * D + cg * 16;
        *(float4*)(jbase + 0)  = jr0;
        *(float4*)(jbase + 4)  = jr1;
        *(float4*)(jbase + 8)  = jr2;
        *(float4*)(jbase + 12) = jr3;
    }
}

extern "C" void kernel_launch(void* const* d_in, const int* in_sizes, int n_in,
                              void* d_out, int out_size, void* d_ws, size_t ws_size,
                              hipStream_t stream) {
    (void)in_sizes; (void)n_in; (void)out_size; (void)ws_size;
    const float* q = (const float*)d_in[0];
    const float* k = (const float*)d_in[1];
    const float* v = (const float*)d_in[2];
    float* out = (float*)d_out;

    float* U      = (float*)d_ws;            // SEQ*D floats (1 MB)
    float* sl     = U + (size_t)SEQ * D;     // SEQ
    float* kqq    = sl + SEQ;                // SEQ
    float* vv     = kqq + SEQ;               // SEQ
    float* kq_adj = vv + SEQ;                // SEQ
    float* vv_adj = kq_adj + SEQ;            // SEQ
    float* kU_adj = vv_adj + SEQ;            // SEQ
    double* invl  = (double*)(kU_adj + SEQ); // SEQ doubles (8B-aligned)

    precompute_kernel<<<SEQ, 256, 0, stream>>>(q, k, v, U, sl, kqq, vv,
                                               kq_adj, vv_adj, kU_adj, invl);
    scan_kernel<<<1, 1024, 0, stream>>>(q, k, v, U, sl, kqq, vv,
                                        kq_adj, vv_adj, kU_adj, invl, out);
}